// Round 7
// baseline (327.710 us; speedup 1.0000x reference)
//
#include <hip/hip_runtime.h>

// Problem constants (from reference): S=7, B=2, C=20, N=30, batch=16384
#define NCH 30
#define RANK_LIMIT 49          // S*S
#define L_COORD 5.0f
#define L_NOOBJ 0.5f

// Exact-cover geometry: 802816 rows * 30 / 4 = 6,021,120 float4 per array.
// 2940 blocks * 256 threads * unroll 8 = 6,021,120 exactly.
#define NB 2940
#define UNROLL 8
#define NBLK_TOTAL (NB + 1)    // + 1 dedicated bbox block

// Native clang vector type — __builtin_nontemporal_load requires a plain
// scalar/vector pointee, not HIP's HIP_vector_type wrapper class.
typedef float vfloat4 __attribute__((ext_vector_type(4)));

// Block-reduce a per-thread value into thread 0 (others get 0).
__device__ inline float block_reduce(float v) {
    #pragma unroll
    for (int off = 32; off > 0; off >>= 1)
        v += __shfl_down(v, off, 64);
    __shared__ float s[4];
    int lane = threadIdx.x & 63, wid = threadIdx.x >> 6;
    if (lane == 0) s[wid] = v;
    __syncthreads();
    return (threadIdx.x == 0) ? (s[0] + s[1] + s[2] + s[3]) : 0.0f;
}

// Last-arrival combine: every block adds its contribution to *acc (device-
// scope atomic — coherent across XCDs), fences, bumps the counter; the block
// that completes the count reads the total via an atomic RMW (coherent read,
// avoids any stale-L2 hazard) and writes the scalar output.
__device__ inline void finish_block(float contrib, float* acc, int* cnt,
                                    float* out) {
    if (threadIdx.x == 0) {
        atomicAdd(acc, contrib);
        __threadfence();
        int old = atomicAdd(cnt, 1);
        if (old == NBLK_TOTAL - 1) {
            float tot = atomicAdd(acc, 0.0f);   // coherent read of final sum
            out[0] = tot;
        }
    }
}

// ---------------------------------------------------------------------------
// Per-row "selected" bbox loss — faithful port of the reference including its
// bugs: x2y2 built from the already-transformed xy; lambda_coord only on the
// x / sqrt(w) terms; selected loss sums l1+l2+l3+IoU; argmax keeps first max.
// ---------------------------------------------------------------------------
__device__ inline float sel_loss(const float* __restrict__ p,
                                 const float* __restrict__ t, int row) {
    const float invS = 1.0f / 7.0f;
    int b0 = row * NCH;
    float tot0 = 0.f, tot1 = 0.f, iou0 = 0.f, iou1 = 0.f;
    #pragma unroll
    for (int j = 0; j < 2; ++j) {
        int o = b0 + 5 * j;
        float px = p[o + 0], py = p[o + 1], pw = p[o + 2], ph = p[o + 3], pc = p[o + 4];
        float tx = t[o + 0], ty = t[o + 1], tw = t[o + 2], th = t[o + 3], tc = t[o + 4];
        float pxy0 = px * invS - 0.5f * pw;
        float pxy1 = py * invS - 0.5f * ph;
        float p2x  = pxy0 * invS + 0.5f * pw;
        float p2y  = pxy1 * invS + 0.5f * ph;
        float txy0 = tx * invS - 0.5f * tw;
        float txy1 = ty * invS - 0.5f * th;
        float t2x  = txy0 * invS + 0.5f * tw;
        float t2y  = txy1 * invS + 0.5f * th;
        float d0 = txy0 - pxy0, d1 = txy1 - pxy1;
        float l1 = L_COORD * d0 * d0 + d1 * d1;
        float s0 = sqrtf(t2x) - sqrtf(p2x);
        float s1 = sqrtf(t2y) - sqrtf(p2y);
        float l2 = L_COORD * s0 * s0 + s1 * s1;
        float dc = tc - pc;
        float l3 = dc * dc;
        float ltx = fmaxf(pxy0, txy0), lty = fmaxf(pxy1, txy1);
        float rbx = fminf(p2x, t2x),   rby = fminf(p2y, t2y);
        float wx  = fmaxf(rbx - ltx, 0.0f);
        float wy  = fmaxf(rby - lty, 0.0f);
        float inter  = wx * wy;
        float area_p = (p2x - pxy0) * (p2y - pxy1);
        float area_t = (t2x - txy0) * (t2y - txy1);
        float io = inter / (area_p + area_t - inter);
        float tt = l1 + l2 + l3 + io;
        if (j == 0) { iou0 = io; tot0 = tt; }
        else        { iou1 = io; tot1 = tt; }
    }
    return (iou1 > iou0) ? tot1 : tot0;   // argmax keeps FIRST max
}

// ---------------------------------------------------------------------------
// Single fused kernel. Blocks [0, NB): nt-float4 noobj streamers (16
// independent loads in flight, no barriers in the stream). Block NB: ordered
// ballot-scan bbox loss (overlapped with the stream). All blocks combine via
// device-scope atomics + last-arrival winner (finish_block).
//
// Channel decode (60-float / 15-float4 two-row groups, pair=i/15, k=i%15):
//   k==1: even-row ch4..7  -> t4 = vt.x (gate+term), p4 = vp.x
//   k==2: even-row ch8..11 -> t9 = vt.y, p9 = vp.y, gate t4 = lane(l-1) vt.x
//   k==8: odd-row  ch2..5  -> t4 = vt.z (gate+term), p4 = vp.z
//   k==9: odd-row  ch6..9  -> t9 = vt.w, p9 = vp.w, gate t4 = lane(l-1) vt.z
// ---------------------------------------------------------------------------
__global__ __launch_bounds__(256) void yolo_kernel(const vfloat4* __restrict__ pv,
                                                   const vfloat4* __restrict__ tv,
                                                   const float* __restrict__ ps,
                                                   const float* __restrict__ ts,
                                                   float* __restrict__ acc,
                                                   int* __restrict__ cnt,
                                                   float* __restrict__ out, int M) {
    const int tid  = threadIdx.x;
    const int lane = tid & 63;

    if (blockIdx.x < NB) {
        // ---- noobj streaming path ----
        const int base = blockIdx.x * (256 * UNROLL) + tid;
        vfloat4 vp[UNROLL], vt[UNROLL];
        #pragma unroll
        for (int u = 0; u < UNROLL; ++u) {
            int i = base + u * 256;
            vp[u] = __builtin_nontemporal_load(&pv[i]);
            vt[u] = __builtin_nontemporal_load(&tv[i]);
        }

        float s_acc = 0.0f;
        #pragma unroll
        for (int u = 0; u < UNROLL; ++u) {
            int i = base + u * 256;
            int pair = i / 15;              // magic-mul
            int k = i - pair * 15;

            float gx = __shfl_up(vt[u].x, 1, 64);
            float gz = __shfl_up(vt[u].z, 1, 64);
            if (lane == 0) {                // wave-boundary fallback (rare)
                if (k == 2) gx = ts[pair * 60 + 4];
                if (k == 9) gz = ts[pair * 60 + 34];
            }

            float d1 = vp[u].x - vt[u].x;
            float d2 = vp[u].y - vt[u].y;
            float d8 = vp[u].z - vt[u].z;
            float d9 = vp[u].w - vt[u].w;

            float c1 = (!(vt[u].x > 0.0f)) ? d1 * d1 : 0.0f;
            float c2 = (!(gx      > 0.0f)) ? d2 * d2 : 0.0f;
            float c8 = (!(vt[u].z > 0.0f)) ? d8 * d8 : 0.0f;
            float c9 = (!(gz      > 0.0f)) ? d9 * d9 : 0.0f;

            s_acc += (k == 1) ? c1 : (k == 2) ? c2 : (k == 8) ? c8
                   : (k == 9) ? c9 : 0.0f;
        }

        float part = block_reduce(s_acc);
        finish_block(L_NOOBJ * part, acc, cnt, out);
    } else {
        // ---- bbox ordered-scan path (one block) ----
        __shared__ int s_wcnt[4];
        __shared__ int s_base;
        if (tid == 0) s_base = 0;
        __syncthreads();

        float local = 0.0f;
        for (int start = 0; start < M; start += 256) {
            int row = start + tid;
            bool obj = false;
            if (row < M) obj = ts[row * NCH + 4] > 0.0f;

            unsigned long long mask = __ballot(obj);
            int wid = tid >> 6;
            if (lane == 0) s_wcnt[wid] = __popcll(mask);
            __syncthreads();

            int base = s_base;
            int off = 0;
            for (int w = 0; w < wid; ++w) off += s_wcnt[w];
            int rank = base + off + __popcll(mask & ((1ULL << lane) - 1ULL));
            if (obj && rank < RANK_LIMIT) local += sel_loss(ps, ts, row);
            __syncthreads();

            if (tid == 0)
                s_base = base + s_wcnt[0] + s_wcnt[1] + s_wcnt[2] + s_wcnt[3];
            __syncthreads();
            if (s_base >= RANK_LIMIT) break;   // uniform exit
        }

        float part = block_reduce(local);
        finish_block(part, acc, cnt, out);
    }
}

extern "C" void kernel_launch(void* const* d_in, const int* in_sizes, int n_in,
                              void* d_out, int out_size, void* d_ws, size_t ws_size,
                              hipStream_t stream) {
    const float* pred = (const float*)d_in[0];
    const float* targ = (const float*)d_in[1];
    float* out = (float*)d_out;
    float* acc = (float*)d_ws;           // ws[0]: float accumulator
    int*   cnt = (int*)d_ws + 1;         // ws[1]: arrival counter

    int M = in_sizes[0] / NCH;           // 802816 rows

    // ws is re-poisoned to 0xAA before every call — zero acc + counter.
    hipMemsetAsync(d_ws, 0, 8, stream);

    yolo_kernel<<<NBLK_TOTAL, 256, 0, stream>>>(
        (const vfloat4*)pred, (const vfloat4*)targ, pred, targ, acc, cnt, out, M);
}

// Round 8
// 193.529 us; speedup vs baseline: 1.6933x; 1.6933x over previous
//
#include <hip/hip_runtime.h>

// Problem constants (from reference): S=7, B=2, C=20, N=30, batch=16384
#define NCH 30
#define RANK_LIMIT 49          // S*S
#define L_COORD 5.0f
#define L_NOOBJ 0.5f

// Exact-cover geometry: 802816 rows * 30 / 4 = 6,021,120 float4 per array.
// 5880 streamer blocks * 256 threads * unroll 4 = 6,021,120 exactly.
#define NB 5880
#define UNROLL 4
#define NBLK_TOTAL (NB + 1)    // + 1 dedicated bbox block

// Native clang vector type — __builtin_nontemporal_load requires a plain
// scalar/vector pointee, not HIP's HIP_vector_type wrapper class.
typedef float vfloat4 __attribute__((ext_vector_type(4)));

// Block-reduce a per-thread value into thread 0 (others get 0).
__device__ inline float block_reduce(float v) {
    #pragma unroll
    for (int off = 32; off > 0; off >>= 1)
        v += __shfl_down(v, off, 64);
    __shared__ float s[4];
    int lane = threadIdx.x & 63, wid = threadIdx.x >> 6;
    if (lane == 0) s[wid] = v;
    __syncthreads();
    return (threadIdx.x == 0) ? (s[0] + s[1] + s[2] + s[3]) : 0.0f;
}

// ---------------------------------------------------------------------------
// Per-row "selected" bbox loss — faithful port of the reference including its
// bugs: x2y2 built from the already-transformed xy; lambda_coord only on the
// x / sqrt(w) terms; selected loss sums l1+l2+l3+IoU; argmax keeps first max.
// ---------------------------------------------------------------------------
__device__ inline float sel_loss(const float* __restrict__ p,
                                 const float* __restrict__ t, int row) {
    const float invS = 1.0f / 7.0f;
    int b0 = row * NCH;
    float tot0 = 0.f, tot1 = 0.f, iou0 = 0.f, iou1 = 0.f;
    #pragma unroll
    for (int j = 0; j < 2; ++j) {
        int o = b0 + 5 * j;
        float px = p[o + 0], py = p[o + 1], pw = p[o + 2], ph = p[o + 3], pc = p[o + 4];
        float tx = t[o + 0], ty = t[o + 1], tw = t[o + 2], th = t[o + 3], tc = t[o + 4];
        float pxy0 = px * invS - 0.5f * pw;
        float pxy1 = py * invS - 0.5f * ph;
        float p2x  = pxy0 * invS + 0.5f * pw;
        float p2y  = pxy1 * invS + 0.5f * ph;
        float txy0 = tx * invS - 0.5f * tw;
        float txy1 = ty * invS - 0.5f * th;
        float t2x  = txy0 * invS + 0.5f * tw;
        float t2y  = txy1 * invS + 0.5f * th;
        float d0 = txy0 - pxy0, d1 = txy1 - pxy1;
        float l1 = L_COORD * d0 * d0 + d1 * d1;
        float s0 = sqrtf(t2x) - sqrtf(p2x);
        float s1 = sqrtf(t2y) - sqrtf(p2y);
        float l2 = L_COORD * s0 * s0 + s1 * s1;
        float dc = tc - pc;
        float l3 = dc * dc;
        float ltx = fmaxf(pxy0, txy0), lty = fmaxf(pxy1, txy1);
        float rbx = fminf(p2x, t2x),   rby = fminf(p2y, t2y);
        float wx  = fmaxf(rbx - ltx, 0.0f);
        float wy  = fmaxf(rby - lty, 0.0f);
        float inter  = wx * wy;
        float area_p = (p2x - pxy0) * (p2y - pxy1);
        float area_t = (t2x - txy0) * (t2y - txy1);
        float io = inter / (area_p + area_t - inter);
        float tt = l1 + l2 + l3 + io;
        if (j == 0) { iou0 = io; tot0 = tt; }
        else        { iou1 = io; tot1 = tt; }
    }
    return (iou1 > iou0) ? tot1 : tot0;   // argmax keeps FIRST max
}

// ---------------------------------------------------------------------------
// Fused main kernel. Blocks [0, NB): nt-float4 noobj streamers (R6-proven:
// UNROLL=4, 8 independent loads in flight, no barriers in the stream). Block
// NB: ordered ballot-scan bbox loss, overlapped with the stream. Every block
// ends with ONE PLAIN STORE of its partial — no atomics, no fences (R7's
// fence+same-line-atomic combine serialized the L2 and tripled the time).
//
// Channel decode (60-float / 15-float4 two-row groups, pair=i/15, k=i%15):
//   k==1: even-row ch4..7  -> t4 = vt.x (gate+term), p4 = vp.x
//   k==2: even-row ch8..11 -> t9 = vt.y, p9 = vp.y, gate t4 = lane(l-1) vt.x
//   k==8: odd-row  ch2..5  -> t4 = vt.z (gate+term), p4 = vp.z
//   k==9: odd-row  ch6..9  -> t9 = vt.w, p9 = vp.w, gate t4 = lane(l-1) vt.z
// ---------------------------------------------------------------------------
__global__ __launch_bounds__(256) void yolo_kernel(const vfloat4* __restrict__ pv,
                                                   const vfloat4* __restrict__ tv,
                                                   const float* __restrict__ ps,
                                                   const float* __restrict__ ts,
                                                   float* __restrict__ partials,
                                                   int M) {
    const int tid  = threadIdx.x;
    const int lane = tid & 63;

    if (blockIdx.x < NB) {
        // ---- noobj streaming path ----
        const int base = blockIdx.x * (256 * UNROLL) + tid;
        vfloat4 vp[UNROLL], vt[UNROLL];
        #pragma unroll
        for (int u = 0; u < UNROLL; ++u) {
            int i = base + u * 256;
            vp[u] = __builtin_nontemporal_load(&pv[i]);
            vt[u] = __builtin_nontemporal_load(&tv[i]);
        }

        float s_acc = 0.0f;
        #pragma unroll
        for (int u = 0; u < UNROLL; ++u) {
            int i = base + u * 256;
            int pair = i / 15;              // magic-mul
            int k = i - pair * 15;

            float gx = __shfl_up(vt[u].x, 1, 64);
            float gz = __shfl_up(vt[u].z, 1, 64);
            if (lane == 0) {                // wave-boundary fallback (rare)
                if (k == 2) gx = ts[pair * 60 + 4];
                if (k == 9) gz = ts[pair * 60 + 34];
            }

            float d1 = vp[u].x - vt[u].x;
            float d2 = vp[u].y - vt[u].y;
            float d8 = vp[u].z - vt[u].z;
            float d9 = vp[u].w - vt[u].w;

            float c1 = (!(vt[u].x > 0.0f)) ? d1 * d1 : 0.0f;
            float c2 = (!(gx      > 0.0f)) ? d2 * d2 : 0.0f;
            float c8 = (!(vt[u].z > 0.0f)) ? d8 * d8 : 0.0f;
            float c9 = (!(gz      > 0.0f)) ? d9 * d9 : 0.0f;

            s_acc += (k == 1) ? c1 : (k == 2) ? c2 : (k == 8) ? c8
                   : (k == 9) ? c9 : 0.0f;
        }

        float part = block_reduce(s_acc);
        if (tid == 0) partials[blockIdx.x] = L_NOOBJ * part;  // plain store
    } else {
        // ---- bbox ordered-scan path (one block, overlapped w/ stream) ----
        __shared__ int s_wcnt[4];
        __shared__ int s_base;
        if (tid == 0) s_base = 0;
        __syncthreads();

        float local = 0.0f;
        for (int start = 0; start < M; start += 256) {
            int row = start + tid;
            bool obj = false;
            if (row < M) obj = ts[row * NCH + 4] > 0.0f;

            unsigned long long mask = __ballot(obj);
            int wid = tid >> 6;
            if (lane == 0) s_wcnt[wid] = __popcll(mask);
            __syncthreads();

            int base = s_base;
            int off = 0;
            for (int w = 0; w < wid; ++w) off += s_wcnt[w];
            int rank = base + off + __popcll(mask & ((1ULL << lane) - 1ULL));
            if (obj && rank < RANK_LIMIT) local += sel_loss(ps, ts, row);
            __syncthreads();

            if (tid == 0)
                s_base = base + s_wcnt[0] + s_wcnt[1] + s_wcnt[2] + s_wcnt[3];
            __syncthreads();
            if (s_base >= RANK_LIMIT) break;   // uniform exit
        }

        float part = block_reduce(local);
        if (tid == 0) partials[NB] = part;     // plain store
    }
}

// ---------------------------------------------------------------------------
// Tiny finish kernel: sum the NB+1 partials (all already scaled) -> out[0].
// Runs after yolo_kernel on the stream; ~3 µs.
// ---------------------------------------------------------------------------
__global__ __launch_bounds__(256) void sum_kernel(const float* __restrict__ partials,
                                                  float* __restrict__ out) {
    float v = 0.0f;
    for (int i = threadIdx.x; i < NBLK_TOTAL; i += 256)
        v += partials[i];
    float tot = block_reduce(v);
    if (threadIdx.x == 0) out[0] = tot;
}

extern "C" void kernel_launch(void* const* d_in, const int* in_sizes, int n_in,
                              void* d_out, int out_size, void* d_ws, size_t ws_size,
                              hipStream_t stream) {
    const float* pred = (const float*)d_in[0];
    const float* targ = (const float*)d_in[1];
    float* out = (float*)d_out;
    float* partials = (float*)d_ws;      // NB+1 floats; all written before read

    int M = in_sizes[0] / NCH;           // 802816 rows

    yolo_kernel<<<NBLK_TOTAL, 256, 0, stream>>>(
        (const vfloat4*)pred, (const vfloat4*)targ, pred, targ, partials, M);
    sum_kernel<<<1, 256, 0, stream>>>(partials, out);
}

// Round 9
// 191.631 us; speedup vs baseline: 1.7101x; 1.0099x over previous
//
#include <hip/hip_runtime.h>

// Problem constants (from reference): S=7, B=2, C=20, N=30, batch=16384
#define NCH 30
#define RANK_LIMIT 49          // S*S
#define L_COORD 5.0f
#define L_NOOBJ 0.5f

// Exact-cover persistent geometry: 802816 rows * 30 / 4 = 6,021,120 float4
// per array = 980 blocks * 256 threads * UNROLL 4 * OUTER 6 exactly.
#define NB 980
#define UNROLL 4
#define OUTER 6
#define CHUNK (256 * UNROLL)         // float4s per block per iteration
#define NBLK_TOTAL (NB + 1)          // + 1 dedicated bbox block

// Native clang vector type — __builtin_nontemporal_load requires a plain
// scalar/vector pointee, not HIP's HIP_vector_type wrapper class.
typedef float vfloat4 __attribute__((ext_vector_type(4)));

// Block-reduce a per-thread value into thread 0 (others get 0).
__device__ inline float block_reduce(float v) {
    #pragma unroll
    for (int off = 32; off > 0; off >>= 1)
        v += __shfl_down(v, off, 64);
    __shared__ float s[4];
    int lane = threadIdx.x & 63, wid = threadIdx.x >> 6;
    if (lane == 0) s[wid] = v;
    __syncthreads();
    return (threadIdx.x == 0) ? (s[0] + s[1] + s[2] + s[3]) : 0.0f;
}

// ---------------------------------------------------------------------------
// Per-row "selected" bbox loss — faithful port of the reference including its
// bugs: x2y2 built from the already-transformed xy; lambda_coord only on the
// x / sqrt(w) terms; selected loss sums l1+l2+l3+IoU; argmax keeps first max.
// ---------------------------------------------------------------------------
__device__ inline float sel_loss(const float* __restrict__ p,
                                 const float* __restrict__ t, int row) {
    const float invS = 1.0f / 7.0f;
    int b0 = row * NCH;
    float tot0 = 0.f, tot1 = 0.f, iou0 = 0.f, iou1 = 0.f;
    #pragma unroll
    for (int j = 0; j < 2; ++j) {
        int o = b0 + 5 * j;
        float px = p[o + 0], py = p[o + 1], pw = p[o + 2], ph = p[o + 3], pc = p[o + 4];
        float tx = t[o + 0], ty = t[o + 1], tw = t[o + 2], th = t[o + 3], tc = t[o + 4];
        float pxy0 = px * invS - 0.5f * pw;
        float pxy1 = py * invS - 0.5f * ph;
        float p2x  = pxy0 * invS + 0.5f * pw;
        float p2y  = pxy1 * invS + 0.5f * ph;
        float txy0 = tx * invS - 0.5f * tw;
        float txy1 = ty * invS - 0.5f * th;
        float t2x  = txy0 * invS + 0.5f * tw;
        float t2y  = txy1 * invS + 0.5f * th;
        float d0 = txy0 - pxy0, d1 = txy1 - pxy1;
        float l1 = L_COORD * d0 * d0 + d1 * d1;
        float s0 = sqrtf(t2x) - sqrtf(p2x);
        float s1 = sqrtf(t2y) - sqrtf(p2y);
        float l2 = L_COORD * s0 * s0 + s1 * s1;
        float dc = tc - pc;
        float l3 = dc * dc;
        float ltx = fmaxf(pxy0, txy0), lty = fmaxf(pxy1, txy1);
        float rbx = fminf(p2x, t2x),   rby = fminf(p2y, t2y);
        float wx  = fmaxf(rbx - ltx, 0.0f);
        float wy  = fmaxf(rby - lty, 0.0f);
        float inter  = wx * wy;
        float area_p = (p2x - pxy0) * (p2y - pxy1);
        float area_t = (t2x - txy0) * (t2y - txy1);
        float io = inter / (area_p + area_t - inter);
        float tt = l1 + l2 + l3 + io;
        if (j == 0) { iou0 = io; tot0 = tt; }
        else        { iou1 = io; tot1 = tt; }
    }
    return (iou1 > iou0) ? tot1 : tot0;   // argmax keeps FIRST max
}

// ---------------------------------------------------------------------------
// Fused main kernel, persistent-streamer variant (m13 shape + nt loads).
// Blocks [0, NB): grid-stride loop, OUTER iterations of UNROLL=4 nt float4
// loads from each array — steady-state software pipelining keeps the vmcnt
// queue full across iterations (single-shot R6/R8 drains it at every block
// boundary). Block NB: ordered ballot-scan bbox loss, overlapped. All blocks
// end with ONE PLAIN STORE of their partial (R7 showed fence+atomic combine
// serializes L2).
//
// Channel decode (60-float / 15-float4 two-row groups, pair=i/15, k=i%15):
//   k==1: even-row ch4..7  -> t4 = vt.x (gate+term), p4 = vp.x
//   k==2: even-row ch8..11 -> t9 = vt.y, p9 = vp.y, gate t4 = lane(l-1) vt.x
//   k==8: odd-row  ch2..5  -> t4 = vt.z (gate+term), p4 = vp.z
//   k==9: odd-row  ch6..9  -> t9 = vt.w, p9 = vp.w, gate t4 = lane(l-1) vt.z
// ---------------------------------------------------------------------------
__global__ __launch_bounds__(256) void yolo_kernel(const vfloat4* __restrict__ pv,
                                                   const vfloat4* __restrict__ tv,
                                                   const float* __restrict__ ps,
                                                   const float* __restrict__ ts,
                                                   float* __restrict__ partials,
                                                   int M) {
    const int tid  = threadIdx.x;
    const int lane = tid & 63;

    if (blockIdx.x < NB) {
        // ---- persistent noobj streaming path ----
        float s_acc = 0.0f;
        int base = blockIdx.x * CHUNK + tid;
        const int step = NB * CHUNK;             // 1,003,520 float4s

        for (int outer = 0; outer < OUTER; ++outer, base += step) {
            vfloat4 vp[UNROLL], vt[UNROLL];
            #pragma unroll
            for (int u = 0; u < UNROLL; ++u) {
                int i = base + u * 256;
                vp[u] = __builtin_nontemporal_load(&pv[i]);
                vt[u] = __builtin_nontemporal_load(&tv[i]);
            }

            #pragma unroll
            for (int u = 0; u < UNROLL; ++u) {
                int i = base + u * 256;
                int pair = i / 15;               // magic-mul
                int k = i - pair * 15;

                float gx = __shfl_up(vt[u].x, 1, 64);
                float gz = __shfl_up(vt[u].z, 1, 64);
                if (lane == 0) {                 // wave-boundary fallback (rare)
                    if (k == 2) gx = ts[pair * 60 + 4];
                    if (k == 9) gz = ts[pair * 60 + 34];
                }

                float d1 = vp[u].x - vt[u].x;
                float d2 = vp[u].y - vt[u].y;
                float d8 = vp[u].z - vt[u].z;
                float d9 = vp[u].w - vt[u].w;

                float c1 = (!(vt[u].x > 0.0f)) ? d1 * d1 : 0.0f;
                float c2 = (!(gx      > 0.0f)) ? d2 * d2 : 0.0f;
                float c8 = (!(vt[u].z > 0.0f)) ? d8 * d8 : 0.0f;
                float c9 = (!(gz      > 0.0f)) ? d9 * d9 : 0.0f;

                s_acc += (k == 1) ? c1 : (k == 2) ? c2 : (k == 8) ? c8
                       : (k == 9) ? c9 : 0.0f;
            }
        }

        float part = block_reduce(s_acc);
        if (tid == 0) partials[blockIdx.x] = L_NOOBJ * part;  // plain store
    } else {
        // ---- bbox ordered-scan path (one block, overlapped w/ stream) ----
        __shared__ int s_wcnt[4];
        __shared__ int s_base;
        if (tid == 0) s_base = 0;
        __syncthreads();

        float local = 0.0f;
        for (int start = 0; start < M; start += 256) {
            int row = start + tid;
            bool obj = false;
            if (row < M) obj = ts[row * NCH + 4] > 0.0f;

            unsigned long long mask = __ballot(obj);
            int wid = tid >> 6;
            if (lane == 0) s_wcnt[wid] = __popcll(mask);
            __syncthreads();

            int base = s_base;
            int off = 0;
            for (int w = 0; w < wid; ++w) off += s_wcnt[w];
            int rank = base + off + __popcll(mask & ((1ULL << lane) - 1ULL));
            if (obj && rank < RANK_LIMIT) local += sel_loss(ps, ts, row);
            __syncthreads();

            if (tid == 0)
                s_base = base + s_wcnt[0] + s_wcnt[1] + s_wcnt[2] + s_wcnt[3];
            __syncthreads();
            if (s_base >= RANK_LIMIT) break;   // uniform exit
        }

        float part = block_reduce(local);
        if (tid == 0) partials[NB] = part;     // plain store
    }
}

// ---------------------------------------------------------------------------
// Tiny finish kernel: sum the NB+1 partials (all already scaled) -> out[0].
// ---------------------------------------------------------------------------
__global__ __launch_bounds__(256) void sum_kernel(const float* __restrict__ partials,
                                                  float* __restrict__ out) {
    float v = 0.0f;
    for (int i = threadIdx.x; i < NBLK_TOTAL; i += 256)
        v += partials[i];
    float tot = block_reduce(v);
    if (threadIdx.x == 0) out[0] = tot;
}

extern "C" void kernel_launch(void* const* d_in, const int* in_sizes, int n_in,
                              void* d_out, int out_size, void* d_ws, size_t ws_size,
                              hipStream_t stream) {
    const float* pred = (const float*)d_in[0];
    const float* targ = (const float*)d_in[1];
    float* out = (float*)d_out;
    float* partials = (float*)d_ws;      // NB+1 floats; all written before read

    int M = in_sizes[0] / NCH;           // 802816 rows

    yolo_kernel<<<NBLK_TOTAL, 256, 0, stream>>>(
        (const vfloat4*)pred, (const vfloat4*)targ, pred, targ, partials, M);
    sum_kernel<<<1, 256, 0, stream>>>(partials, out);
}